// Round 3
// baseline (170.255 us; speedup 1.0000x reference)
//
#include <hip/hip_runtime.h>

#define E_CONST 3
#define T_CONST 100
#define C10 10.0f
#define ALPHA_C 0.05f
#define SPLIT 4

__device__ inline int waveInclScan(int v, int lane) {
    #pragma unroll
    for (int off = 1; off < 64; off <<= 1) {
        int n = __shfl_up(v, off, 64);
        if (lane >= off) v += n;
    }
    return v;
}

// ---------------------------------------------------------------------------
// combo (512 thr): blocks [0, prepBlocks) run prep (64 rows/block: contiguous
// float4 loads -> LDS tile -> bit-identical sequential row scan -> coalesced
// transposed stores); blocks [prepBlocks, prepBlocks+E) run sortmeta (LDS
// histogram + shuffle scan + counting-sort scatter), now with half the serial
// chunk depth. Block 0 also zeroes the done-counter for grouppair.
// ---------------------------------------------------------------------------
__global__ __launch_bounds__(512) void combo_kernel(
    const float* __restrict__ event_out, const int* __restrict__ et,
    const int* __restrict__ labs, float* __restrict__ cumT,
    int* __restrict__ perm, int* __restrict__ permB,
    int* __restrict__ binStartA, int* __restrict__ b1endA,
    int* __restrict__ cnt, int prepBlocks, int S)
{
    __shared__ float tile[64][101];        // 25.9 KB; pad 101 -> scan reads 2-way free
    __shared__ int histK[2 * T_CONST];
    __shared__ int histB[T_CONST];
    __shared__ int cursK[2 * T_CONST];
    __shared__ int cursB[T_CONST];
    __shared__ int wsK[8], wsB[8];

    const int tid = threadIdx.x;

    if ((int)blockIdx.x < prepBlocks) {
        // ---------------- prep half: 64 rows per block ----------------
        if (blockIdx.x == 0 && tid == 0) *cnt = 0;   // reset grouppair done-counter
        const int rowbase = (int)blockIdx.x * 64;              // in [0, E*S)
        const float4* __restrict__ src =
            reinterpret_cast<const float4*>(event_out) + (size_t)rowbase * 25;
        for (int idx = tid; idx < 64 * 25; idx += 512) {       // contiguous 25.6KB
            const float4 v = src[idx];
            const int r = idx / 25;
            const int c = idx - r * 25;
            float* d = &tile[r][c * 4];
            d[0] = v.x; d[1] = v.y; d[2] = v.z; d[3] = v.w;
        }
        __syncthreads();
        if (tid < 64) {                                        // same add order as before
            float run = 0.f;
            #pragma unroll 4
            for (int c = 0; c < T_CONST; ++c) { run += tile[tid][c]; tile[tid][c] = run; }
        }
        __syncthreads();
        const int i  = rowbase / S;
        const int s0 = rowbase - i * S;
        float* __restrict__ dst = cumT + (size_t)i * T_CONST * S + s0;
        for (int idx = tid; idx < 64 * T_CONST; idx += 512) {  // coalesced 256B/wave
            const int t = idx >> 6;
            const int r = idx & 63;
            dst[(size_t)t * S + r] = tile[r][t];
        }
        return;
    }

    // ---------------- sortmeta half (one block per event) ----------------
    const int i = (int)blockIdx.x - prepBlocks;
    const int lane = tid & 63, wid = tid >> 6;

    for (int b = tid; b < 2 * T_CONST; b += 512) histK[b] = 0;
    for (int b = tid; b < T_CONST; b += 512) histB[b] = 0;
    __syncthreads();

    for (int s0 = tid; s0 < S; s0 += 2048) {
        const int sB = s0 + 512, sC = s0 + 1024, sD = s0 + 1536;
        const int tA = et[s0 * E_CONST + i];
        const int lA = labs[s0 * E_CONST + i];
        int tB = 0, lB = 0, tC = 0, lC = 0, tD = 0, lD = 0;
        if (sB < S) { tB = et[sB * E_CONST + i]; lB = labs[sB * E_CONST + i]; }
        if (sC < S) { tC = et[sC * E_CONST + i]; lC = labs[sC * E_CONST + i]; }
        if (sD < S) { tD = et[sD * E_CONST + i]; lD = labs[sD * E_CONST + i]; }
        atomicAdd(&histK[tA * 2 + (1 - lA)], 1); if (lA) atomicAdd(&histB[tA], 1);
        if (sB < S) { atomicAdd(&histK[tB * 2 + (1 - lB)], 1); if (lB) atomicAdd(&histB[tB], 1); }
        if (sC < S) { atomicAdd(&histK[tC * 2 + (1 - lC)], 1); if (lC) atomicAdd(&histB[tC], 1); }
        if (sD < S) { atomicAdd(&histK[tD * 2 + (1 - lD)], 1); if (lD) atomicAdd(&histB[tD], 1); }
    }
    __syncthreads();

    const int vK = (tid < 2 * T_CONST) ? histK[tid] : 0;
    int inclK = waveInclScan(vK, lane);
    const int vB = (tid < T_CONST) ? histB[tid] : 0;
    int inclB = waveInclScan(vB, lane);
    if (lane == 63) { wsK[wid] = inclK; wsB[wid] = inclB; }
    __syncthreads();
    int offK = 0, offB = 0;
    for (int w = 0; w < wid; ++w) { offK += wsK[w]; offB += wsB[w]; }
    inclK += offK; inclB += offB;
    const int exclK = inclK - vK;
    const int exclB = inclB - vB;

    if (tid < 2 * T_CONST) {
        cursK[tid] = exclK;
        binStartA[i * 2 * T_CONST + tid] = exclK;
    }
    if (tid < T_CONST) {
        cursB[tid] = exclB;
        b1endA[i * T_CONST + tid] = inclB;
    }
    __syncthreads();

    for (int s0 = tid; s0 < S; s0 += 2048) {
        const int sB = s0 + 512, sC = s0 + 1024, sD = s0 + 1536;
        const int tA = et[s0 * E_CONST + i];
        const int lA = labs[s0 * E_CONST + i];
        int tB = 0, lB = 0, tC = 0, lC = 0, tD = 0, lD = 0;
        if (sB < S) { tB = et[sB * E_CONST + i]; lB = labs[sB * E_CONST + i]; }
        if (sC < S) { tC = et[sC * E_CONST + i]; lC = labs[sC * E_CONST + i]; }
        if (sD < S) { tD = et[sD * E_CONST + i]; lD = labs[sD * E_CONST + i]; }

        int slot = atomicAdd(&cursK[tA * 2 + (1 - lA)], 1);
        perm[i * S + slot] = s0;
        if (lA) { const int sb = atomicAdd(&cursB[tA], 1); permB[i * S + sb] = s0; }
        if (sB < S) {
            slot = atomicAdd(&cursK[tB * 2 + (1 - lB)], 1);
            perm[i * S + slot] = sB;
            if (lB) { const int sb = atomicAdd(&cursB[tB], 1); permB[i * S + sb] = sB; }
        }
        if (sC < S) {
            slot = atomicAdd(&cursK[tC * 2 + (1 - lC)], 1);
            perm[i * S + slot] = sC;
            if (lC) { const int sb = atomicAdd(&cursB[tC], 1); permB[i * S + sb] = sC; }
        }
        if (sD < S) {
            slot = atomicAdd(&cursK[tD * 2 + (1 - lD)], 1);
            perm[i * S + slot] = sD;
            if (lD) { const int sb = atomicAdd(&cursB[tD], 1); permB[i * S + sb] = sD; }
        }
    }
}

// ---------------------------------------------------------------------------
// grouppair v2: one block per (event, t-bin, direction, range-split). Stage
// exp(range) in LDS once; sweep with 128 thresholds/pass (4 per thread in
// registers) -> nkc==1 for nearly all groups, LDS traffic /2.5-3. Per-term
// math unchanged (same __expf inputs, same compares, same 1/t factors).
// Last finishing block does a fixed-order (deterministic) final reduction.
// ---------------------------------------------------------------------------
__global__ __launch_bounds__(256) void grouppair_kernel(
    const float* __restrict__ cumT, const int* __restrict__ perm,
    const int* __restrict__ permB, const int* __restrict__ binStartA,
    const int* __restrict__ b1endA, float* __restrict__ partials,
    int* __restrict__ cnt, float* __restrict__ out, int S, int nBlocks)
{
    __shared__ __align__(16) float elds[2048];
    __shared__ float wsum[4];
    __shared__ int lastFlag;
    const int tid = threadIdx.x;

    int x = (int)blockIdx.x;
    const int sp = x & (SPLIT - 1); x >>= 2;
    const int dir = x & 1;          x >>= 1;
    const int tt = x % T_CONST;
    const int i  = x / T_CONST;

    const int* __restrict__ bs = binStartA + i * 2 * T_CONST;
    int kbeg = 0, kend = 0, rbeg = 0, rlen = 0, colIdx = 0;
    bool active = true;
    if (dir == 0) {
        kbeg = bs[2 * tt];
        kend = bs[2 * tt + 1];
        rbeg = kend;
        rlen = S - rbeg;
        colIdx = tt;
    } else {
        const int cb = (T_CONST - 2) - tt;      // big (large cb) first
        if (cb < 0) active = false;
        else {
            kbeg = (cb == 0) ? bs[2] : bs[2 * cb + 1];
            kend = bs[2 * cb + 3];
            rbeg = 0;
            rlen = b1endA[i * T_CONST + cb];
            colIdx = cb;
        }
    }
    const int K = kend - kbeg;
    if (K <= 0 || rlen <= 0) active = false;

    float blocktot = 0.f;
    if (active) {
        const int qbeg = rbeg + (rlen * sp) / SPLIT;
        const int qend = rbeg + (rlen * (sp + 1)) / SPLIT;
        const int qn   = qend - qbeg;                   // <= ceil(8192/4) = 2048
        const int qnp  = (qn + 3) & ~3;

        const float* __restrict__ col = cumT + ((size_t)i * T_CONST + colIdx) * S;
        const int* __restrict__ pidx = (dir == 0 ? perm : permB) + i * S;
        const float sgn = (dir == 0) ? C10 : -C10;

        for (int idx = tid; idx < qnp; idx += 256) {
            float e = 0.f;                               // pad: e>thr never true
            if (idx < qn) e = __expf(sgn * col[pidx[qbeg + idx]]);
            elds[idx] = e;
        }
        __syncthreads();

        const int kq4 = (tid & 31) * 4;      // 4 consecutive thresholds per thread
        const int ep  = tid >> 5;            // element strip 0..7
        const int qn4 = qnp >> 2;
        const float4* __restrict__ e4 = reinterpret_cast<const float4*>(elds);
        const int permBase = i * S;
        const int nkc = (K + 127) >> 7;

        for (int kc = 0; kc < nkc; ++kc) {
            const int jb = kbeg + (kc << 7) + kq4;
            float thr0 = 1e30f, thr1 = 1e30f, thr2 = 1e30f, thr3 = 1e30f;
            float f0 = 0.f, f1 = 0.f, f2 = 0.f, f3 = 0.f;
            if (jb + 0 < kend) { const float tv = __expf(C10 * col[perm[permBase + jb + 0]]);
                if (dir == 0) { thr0 = tv; f0 = 1.0f / tv; } else { thr0 = 1.0f / tv; f0 = tv; } }
            if (jb + 1 < kend) { const float tv = __expf(C10 * col[perm[permBase + jb + 1]]);
                if (dir == 0) { thr1 = tv; f1 = 1.0f / tv; } else { thr1 = 1.0f / tv; f1 = tv; } }
            if (jb + 2 < kend) { const float tv = __expf(C10 * col[perm[permBase + jb + 2]]);
                if (dir == 0) { thr2 = tv; f2 = 1.0f / tv; } else { thr2 = 1.0f / tv; f2 = tv; } }
            if (jb + 3 < kend) { const float tv = __expf(C10 * col[perm[permBase + jb + 3]]);
                if (dir == 0) { thr3 = tv; f3 = 1.0f / tv; } else { thr3 = 1.0f / tv; f3 = tv; } }

            float a0 = 0.f, a1 = 0.f, a2 = 0.f, a3 = 0.f;
            for (int q = ep; q < qn4; q += 8) {          // LDS broadcast reads
                const float4 v = e4[q];
                a0 += (v.x > thr0) ? v.x : 0.f;
                a0 += (v.y > thr0) ? v.y : 0.f;
                a0 += (v.z > thr0) ? v.z : 0.f;
                a0 += (v.w > thr0) ? v.w : 0.f;
                a1 += (v.x > thr1) ? v.x : 0.f;
                a1 += (v.y > thr1) ? v.y : 0.f;
                a1 += (v.z > thr1) ? v.z : 0.f;
                a1 += (v.w > thr1) ? v.w : 0.f;
                a2 += (v.x > thr2) ? v.x : 0.f;
                a2 += (v.y > thr2) ? v.y : 0.f;
                a2 += (v.z > thr2) ? v.z : 0.f;
                a2 += (v.w > thr2) ? v.w : 0.f;
                a3 += (v.x > thr3) ? v.x : 0.f;
                a3 += (v.y > thr3) ? v.y : 0.f;
                a3 += (v.z > thr3) ? v.z : 0.f;
                a3 += (v.w > thr3) ? v.w : 0.f;
            }
            blocktot += a0 * f0 + a1 * f1 + a2 * f2 + a3 * f3;
        }
    }

    for (int off = 32; off > 0; off >>= 1) blocktot += __shfl_down(blocktot, off, 64);
    const int lane = tid & 63, wid = tid >> 6;
    if (lane == 0) wsum[wid] = blocktot;
    __syncthreads();
    if (tid == 0) {
        partials[blockIdx.x] = wsum[0] + wsum[1] + wsum[2] + wsum[3];
        __threadfence();                                  // release partials
        const int prev = atomicAdd(cnt, 1);               // device-scope
        lastFlag = (prev == nBlocks - 1) ? 1 : 0;
    }
    __syncthreads();
    if (lastFlag) {                                       // block-uniform
        __threadfence();                                  // acquire
        float s0 = 0.f;
        for (int idx = tid; idx < nBlocks; idx += 256) s0 += partials[idx];  // fixed order
        float sum = s0;
        for (int off = 32; off > 0; off >>= 1) sum += __shfl_down(sum, off, 64);
        if (lane == 0) wsum[wid] = sum;
        __syncthreads();
        if (tid == 0) out[0] = ALPHA_C * (wsum[0] + wsum[1] + wsum[2] + wsum[3]);
    }
}

// ---------------------------------------------------------------------------
// reduce: used only by the fallback path.
// ---------------------------------------------------------------------------
__global__ __launch_bounds__(1024) void reduce_kernel(
    const float* __restrict__ partials, int n, float* __restrict__ out)
{
    const int tid = threadIdx.x;
    float s0 = 0.f, s1 = 0.f, s2 = 0.f, s3 = 0.f;
    const int n4 = n & ~3;
    for (int idx = tid * 4; idx < n4; idx += 4096) {
        const float4 v = *reinterpret_cast<const float4*>(partials + idx);
        s0 += v.x; s1 += v.y; s2 += v.z; s3 += v.w;
    }
    for (int idx = n4 + tid; idx < n; idx += 1024) s0 += partials[idx];
    float sum = (s0 + s1) + (s2 + s3);
    for (int off = 32; off > 0; off >>= 1) sum += __shfl_down(sum, off, 64);
    __shared__ float wsum[16];
    const int lane = tid & 63, wd = tid >> 6;
    if (lane == 0) wsum[wd] = sum;
    __syncthreads();
    if (tid == 0) {
        float t = 0.f;
        for (int w = 0; w < 16; ++w) t += wsum[w];
        out[0] = ALPHA_C * t;
    }
}

// ---------------------------------------------------------------------------
// fallback (R1-proven structure): used only if ws_size is too small.
// ---------------------------------------------------------------------------
__global__ __launch_bounds__(64) void prep_fb_kernel(
    const float* __restrict__ event_out, const int* __restrict__ et,
    const int* __restrict__ labs, float* __restrict__ cumT,
    int* __restrict__ tlA, int S)
{
    const int gid = blockIdx.x * 64 + threadIdx.x;
    const int i = gid / S;
    const int s = gid - i * S;
    const float4* __restrict__ row =
        reinterpret_cast<const float4*>(event_out + (size_t)gid * T_CONST);
    float* __restrict__ base = cumT + (size_t)i * T_CONST * S + s;
    float run = 0.f;
    #pragma unroll
    for (int c = 0; c < T_CONST / 4; ++c) {
        const float4 v = row[c];
        const float c0 = run + v.x;
        const float c1 = c0 + v.y;
        const float c2 = c1 + v.z;
        const float c3 = c2 + v.w;
        base[(size_t)(4 * c + 0) * S] = c0;
        base[(size_t)(4 * c + 1) * S] = c1;
        base[(size_t)(4 * c + 2) * S] = c2;
        base[(size_t)(4 * c + 3) * S] = c3;
        run = c3;
    }
    const int t   = et[s * E_CONST + i];
    const int lab = labs[s * E_CONST + i];
    tlA[i * S + s] = (t & 0xffff) | (lab << 16);
}

__global__ __launch_bounds__(256) void pair_fb_kernel(
    const float* __restrict__ cumT, const int* __restrict__ tlA,
    float* __restrict__ partials, int S)
{
    const int bx = blockIdx.x;
    const int i = bx / S;
    const int k = bx - i * S;
    const int base = i * S;
    const int tlk = tlA[base + k];
    const int t_k = tlk & 0xffff;
    const int lab_k = tlk >> 16;
    const bool doF = (lab_k == 1);
    const bool doB = (t_k > 0);
    float sum = 0.f;
    if (doF || doB) {
        const int cb = lab_k ? (t_k > 0 ? t_k - 1 : 0) : t_k;
        const float* __restrict__ colF = cumT + ((size_t)i * T_CONST + t_k) * S;
        const float* __restrict__ colB = cumT + ((size_t)i * T_CONST + cb)  * S;
        const float vf_k = colF[k];
        const float vb_k = colB[k];
        const int* __restrict__ tlp = tlA + base;
        for (int s = threadIdx.x; s < S; s += 256) {
            const int tls = tlp[s];
            const int t_s = tls & 0xffff;
            const int lab_s = tls >> 16;
            if (doF) {
                const float vs = colF[s];
                const bool c = (t_s > t_k) | ((t_s == t_k) & (lab_s == 0));
                if (c & (vs > vf_k)) sum += __expf((vs - vf_k) * C10);
            }
            if (doB) {
                const float vs = colB[s];
                const bool c = (t_s <= cb) & (lab_s == 1);
                if (c & (vb_k > vs)) sum += __expf((vb_k - vs) * C10);
            }
        }
    }
    for (int off = 32; off > 0; off >>= 1) sum += __shfl_down(sum, off, 64);
    __shared__ float wsum[4];
    const int lane = threadIdx.x & 63, wd = threadIdx.x >> 6;
    if (lane == 0) wsum[wd] = sum;
    __syncthreads();
    if (threadIdx.x == 0) partials[bx] = wsum[0] + wsum[1] + wsum[2] + wsum[3];
}

extern "C" void kernel_launch(void* const* d_in, const int* in_sizes, int n_in,
                              void* d_out, int out_size, void* d_ws, size_t ws_size,
                              hipStream_t stream)
{
    const float* event_out = (const float*)d_in[0];  // (E,S,T) fp32
    const int*   et        = (const int*)d_in[1];    // (S,E) int32
    const int*   labsp     = (const int*)d_in[2];    // (S,E) int32
    const int S = in_sizes[1] / E_CONST;             // 8192

    const size_t colElems = (size_t)E_CONST * T_CONST * S;
    const size_t esElems  = (size_t)E_CONST * S;
    const int    gpBlocks = E_CONST * T_CONST * 2 * SPLIT;   // 2400

    char* p = (char*)d_ws;
    float* cumT     = (float*)p; p += colElems * 4;
    int*   perm     = (int*)p;   p += esElems * 4;
    int*   permB    = (int*)p;   p += esElems * 4;
    int*   binStart = (int*)p;   p += (size_t)E_CONST * 2 * T_CONST * 4;
    int*   b1end    = (int*)p;   p += (size_t)E_CONST * T_CONST * 4;
    float* partials = (float*)p; p += (size_t)gpBlocks * 4;
    int*   cnt      = (int*)p;   p += 4;
    const size_t needed = (size_t)(p - (char*)d_ws);
    const size_t fallback_needed = colElems * 4 + esElems * 4 * 2;

    const int prepBlocks = (E_CONST * S) / 64;       // 384 (S % 64 == 0)

    if (ws_size >= needed && (E_CONST * S) % 64 == 0) {
        hipLaunchKernelGGL(combo_kernel, dim3(prepBlocks + E_CONST), dim3(512), 0, stream,
                           event_out, et, labsp, cumT, perm, permB,
                           binStart, b1end, cnt, prepBlocks, S);
        hipLaunchKernelGGL(grouppair_kernel, dim3(gpBlocks), dim3(256), 0, stream,
                           cumT, perm, permB, binStart, b1end, partials,
                           cnt, (float*)d_out, S, gpBlocks);
    } else if (ws_size >= fallback_needed) {
        const int nB = E_CONST * S;
        float* cumT2     = (float*)d_ws;
        int*   tlA2      = (int*)(cumT2 + colElems);
        float* partials2 = (float*)(tlA2 + esElems);
        hipLaunchKernelGGL(prep_fb_kernel, dim3(E_CONST * S / 64), dim3(64), 0, stream,
                           event_out, et, labsp, cumT2, tlA2, S);
        hipLaunchKernelGGL(pair_fb_kernel, dim3(nB), dim3(256), 0, stream,
                           cumT2, tlA2, partials2, S);
        hipLaunchKernelGGL(reduce_kernel, dim3(1), dim3(1024), 0, stream,
                           partials2, nB, (float*)d_out);
    }
}

// Round 4
// 107.111 us; speedup vs baseline: 1.5895x; 1.5895x over previous
//
#include <hip/hip_runtime.h>

#define E_CONST 3
#define T_CONST 100
#define C10 10.0f
#define ALPHA_C 0.05f
#define SPLIT 4

__device__ inline int waveInclScan(int v, int lane) {
    #pragma unroll
    for (int off = 1; off < 64; off <<= 1) {
        int n = __shfl_up(v, off, 64);
        if (lane >= off) v += n;
    }
    return v;
}

// ---------------------------------------------------------------------------
// combo (512 thr): blocks [0, prepBlocks) run prep (64 rows/block: contiguous
// float4 loads -> LDS tile -> bit-identical sequential row scan -> coalesced
// transposed stores); blocks [prepBlocks, prepBlocks+E) run sortmeta (LDS
// histogram + shuffle scan + counting-sort scatter; B-side removed — grouppair
// v3 derives membership directly from et/labs).
// ---------------------------------------------------------------------------
__global__ __launch_bounds__(512) void combo_kernel(
    const float* __restrict__ event_out, const int* __restrict__ et,
    const int* __restrict__ labs, float* __restrict__ cumT,
    int* __restrict__ perm, int* __restrict__ binStartA,
    int prepBlocks, int S)
{
    __shared__ float tile[64][101];        // 25.9 KB; pad 101 -> scan reads 2-way free
    __shared__ int histK[2 * T_CONST];
    __shared__ int cursK[2 * T_CONST];
    __shared__ int wsK[8];

    const int tid = threadIdx.x;

    if ((int)blockIdx.x < prepBlocks) {
        // ---------------- prep half: 64 rows per block ----------------
        const int rowbase = (int)blockIdx.x * 64;              // in [0, E*S)
        const float4* __restrict__ src =
            reinterpret_cast<const float4*>(event_out) + (size_t)rowbase * 25;
        for (int idx = tid; idx < 64 * 25; idx += 512) {       // contiguous 25.6KB
            const float4 v = src[idx];
            const int r = idx / 25;
            const int c = idx - r * 25;
            float* d = &tile[r][c * 4];
            d[0] = v.x; d[1] = v.y; d[2] = v.z; d[3] = v.w;
        }
        __syncthreads();
        if (tid < 64) {                                        // same add order as before
            float run = 0.f;
            #pragma unroll 4
            for (int c = 0; c < T_CONST; ++c) { run += tile[tid][c]; tile[tid][c] = run; }
        }
        __syncthreads();
        const int i  = rowbase / S;
        const int s0 = rowbase - i * S;
        float* __restrict__ dst = cumT + (size_t)i * T_CONST * S + s0;
        for (int idx = tid; idx < 64 * T_CONST; idx += 512) {  // coalesced 256B/wave
            const int t = idx >> 6;
            const int r = idx & 63;
            dst[(size_t)t * S + r] = tile[r][t];
        }
        return;
    }

    // ---------------- sortmeta half (one block per event) ----------------
    const int i = (int)blockIdx.x - prepBlocks;
    const int lane = tid & 63, wid = tid >> 6;

    for (int b = tid; b < 2 * T_CONST; b += 512) histK[b] = 0;
    __syncthreads();

    for (int s0 = tid; s0 < S; s0 += 2048) {
        const int sB = s0 + 512, sC = s0 + 1024, sD = s0 + 1536;
        const int tA = et[s0 * E_CONST + i];
        const int lA = labs[s0 * E_CONST + i];
        int tB = 0, lB = 0, tC = 0, lC = 0, tD = 0, lD = 0;
        if (sB < S) { tB = et[sB * E_CONST + i]; lB = labs[sB * E_CONST + i]; }
        if (sC < S) { tC = et[sC * E_CONST + i]; lC = labs[sC * E_CONST + i]; }
        if (sD < S) { tD = et[sD * E_CONST + i]; lD = labs[sD * E_CONST + i]; }
        atomicAdd(&histK[tA * 2 + (1 - lA)], 1);
        if (sB < S) atomicAdd(&histK[tB * 2 + (1 - lB)], 1);
        if (sC < S) atomicAdd(&histK[tC * 2 + (1 - lC)], 1);
        if (sD < S) atomicAdd(&histK[tD * 2 + (1 - lD)], 1);
    }
    __syncthreads();

    const int vK = (tid < 2 * T_CONST) ? histK[tid] : 0;
    int inclK = waveInclScan(vK, lane);
    if (lane == 63) wsK[wid] = inclK;
    __syncthreads();
    int offK = 0;
    for (int w = 0; w < wid; ++w) offK += wsK[w];
    inclK += offK;
    const int exclK = inclK - vK;

    if (tid < 2 * T_CONST) {
        cursK[tid] = exclK;
        binStartA[i * 2 * T_CONST + tid] = exclK;
    }
    __syncthreads();

    for (int s0 = tid; s0 < S; s0 += 2048) {
        const int sB = s0 + 512, sC = s0 + 1024, sD = s0 + 1536;
        const int tA = et[s0 * E_CONST + i];
        const int lA = labs[s0 * E_CONST + i];
        int tB = 0, lB = 0, tC = 0, lC = 0, tD = 0, lD = 0;
        if (sB < S) { tB = et[sB * E_CONST + i]; lB = labs[sB * E_CONST + i]; }
        if (sC < S) { tC = et[sC * E_CONST + i]; lC = labs[sC * E_CONST + i]; }
        if (sD < S) { tD = et[sD * E_CONST + i]; lD = labs[sD * E_CONST + i]; }

        int slot = atomicAdd(&cursK[tA * 2 + (1 - lA)], 1);
        perm[i * S + slot] = s0;
        if (sB < S) { slot = atomicAdd(&cursK[tB * 2 + (1 - lB)], 1); perm[i * S + slot] = sB; }
        if (sC < S) { slot = atomicAdd(&cursK[tC * 2 + (1 - lC)], 1); perm[i * S + slot] = sC; }
        if (sD < S) { slot = atomicAdd(&cursK[tD * 2 + (1 - lD)], 1); perm[i * S + slot] = sD; }
    }
}

// ---------------------------------------------------------------------------
// grouppair v3: one block per (event, t-bin, direction, S/4-chunk). Stage
// phase reads the chunk COALESCED (col[s], et[s], labs[s] - no gathers),
// computes e = exp(+-10*col[s]) (identical per-term math), tests membership
// directly:
//   fwd(col t):  t_s > t  |  (t_s == t & lab_s == 0)     == perm-range [bs[2t+1],S)
//   bwd(col cb): t_s <= cb & lab_s == 1                  == permB-range [0,b1end[cb])
// then compacts members into LDS via a deterministic block scan (register-held
// elements). Sweep: proven 32-thresholds/pass, 8-strip broadcast form.
// ---------------------------------------------------------------------------
__global__ __launch_bounds__(256) void grouppair_kernel(
    const float* __restrict__ cumT, const int* __restrict__ perm,
    const int* __restrict__ et, const int* __restrict__ labs,
    const int* __restrict__ binStartA, float* __restrict__ partials, int S)
{
    __shared__ __align__(16) float elds[2048];
    __shared__ float wsum[4];
    __shared__ int wcnt[4];
    __shared__ int nTot;
    const int tid = threadIdx.x;
    const int lane = tid & 63, wid = tid >> 6;

    int x = (int)blockIdx.x;
    const int sp = x & (SPLIT - 1); x >>= 2;
    const int dir = x & 1;          x >>= 1;
    const int tt = x % T_CONST;
    const int i  = x / T_CONST;

    const int* __restrict__ bs = binStartA + i * 2 * T_CONST;
    int kbeg = 0, kend = 0, colIdx = 0, tref = 0;
    bool active = true;                     // block-uniform
    if (dir == 0) {
        kbeg = bs[2 * tt]; kend = bs[2 * tt + 1]; colIdx = tt; tref = tt;
    } else {
        const int cb = (T_CONST - 2) - tt;
        if (cb < 0) active = false;
        else { kbeg = (cb == 0) ? bs[2] : bs[2 * cb + 1]; kend = bs[2 * cb + 3];
               colIdx = cb; tref = cb; }
    }
    const int K = kend - kbeg;
    if (K <= 0) active = false;

    float blocktot = 0.f;
    if (active) {                           // block-uniform branch
        const int chunk = S / SPLIT;        // 2048 (launcher guarantees)
        const int cbeg = sp * chunk;
        const float* __restrict__ col = cumT + ((size_t)i * T_CONST + colIdx) * S;
        const float sgn = (dir == 0) ? C10 : -C10;

        // phase 1: coalesced chunk read, e + membership in registers
        float ev[8];
        int mask = 0, m = 0;
        #pragma unroll
        for (int j = 0; j < 8; ++j) {
            const int s = cbeg + tid + j * 256;
            const int ts = et[s * E_CONST + i];
            const int ls = labs[s * E_CONST + i];
            const bool mem = (dir == 0)
                ? ((ts > tref) | ((ts == tref) & (ls == 0)))
                : ((ts <= tref) & (ls == 1));
            ev[j] = __expf(sgn * col[s]);
            if (mem) { mask |= (1 << j); ++m; }
        }
        // phase 2: deterministic block exclusive scan of per-thread counts
        const int incl = waveInclScan(m, lane);
        if (lane == 63) wcnt[wid] = incl;
        __syncthreads();
        int off = 0;
        for (int w = 0; w < wid; ++w) off += wcnt[w];
        int base = incl - m + off;
        // phase 3: compact members into LDS (thread-ordered, deterministic)
        #pragma unroll
        for (int j = 0; j < 8; ++j)
            if (mask & (1 << j)) elds[base++] = ev[j];
        if (tid == 255) {                   // base now == total member count
            const int n = base;
            nTot = n;
            const int np = (n + 3) & ~3;
            for (int p = n; p < np; ++p) elds[p] = 0.f;   // float4 pad
        }
        __syncthreads();

        const int n = nTot;
        if (n > 0) {                        // block-uniform
            const int qn4 = ((n + 3) & ~3) >> 2;
            const int kq = tid & 31;        // threshold lane
            const int ep = tid >> 5;        // element strip 0..7
            const float4* __restrict__ e4 = reinterpret_cast<const float4*>(elds);
            const int permBase = i * S;
            const int nkc = (K + 31) >> 5;

            for (int kc = 0; kc < nkc; ++kc) {
                const int j = kbeg + (kc << 5) + kq;
                float thr = 1e30f, factor = 0.f;
                if (j < kend) {
                    const float tval = __expf(C10 * col[perm[permBase + j]]);
                    if (dir == 0) { thr = tval;        factor = 1.0f / tval; }
                    else          { thr = 1.0f / tval; factor = tval; }
                }
                float acc = 0.f;
                for (int q = ep; q < qn4; q += 8) {     // LDS broadcast reads
                    const float4 v = e4[q];
                    acc += (v.x > thr) ? v.x : 0.f;
                    acc += (v.y > thr) ? v.y : 0.f;
                    acc += (v.z > thr) ? v.z : 0.f;
                    acc += (v.w > thr) ? v.w : 0.f;
                }
                blocktot += acc * factor;
            }
        }
    }

    for (int off = 32; off > 0; off >>= 1) blocktot += __shfl_down(blocktot, off, 64);
    if (lane == 0) wsum[wid] = blocktot;
    __syncthreads();
    if (tid == 0) partials[blockIdx.x] = wsum[0] + wsum[1] + wsum[2] + wsum[3];
}

// ---------------------------------------------------------------------------
// reduce: float4 loads, 4 independent accumulators. tail-safe.
// ---------------------------------------------------------------------------
__global__ __launch_bounds__(1024) void reduce_kernel(
    const float* __restrict__ partials, int n, float* __restrict__ out)
{
    const int tid = threadIdx.x;
    float s0 = 0.f, s1 = 0.f, s2 = 0.f, s3 = 0.f;
    const int n4 = n & ~3;
    for (int idx = tid * 4; idx < n4; idx += 4096) {
        const float4 v = *reinterpret_cast<const float4*>(partials + idx);
        s0 += v.x; s1 += v.y; s2 += v.z; s3 += v.w;
    }
    for (int idx = n4 + tid; idx < n; idx += 1024) s0 += partials[idx];
    float sum = (s0 + s1) + (s2 + s3);
    for (int off = 32; off > 0; off >>= 1) sum += __shfl_down(sum, off, 64);
    __shared__ float wsum[16];
    const int lane = tid & 63, wd = tid >> 6;
    if (lane == 0) wsum[wd] = sum;
    __syncthreads();
    if (tid == 0) {
        float t = 0.f;
        for (int w = 0; w < 16; ++w) t += wsum[w];
        out[0] = ALPHA_C * t;
    }
}

// ---------------------------------------------------------------------------
// fallback (R1-proven structure): used only if ws_size is too small or shape
// assumptions don't hold.
// ---------------------------------------------------------------------------
__global__ __launch_bounds__(64) void prep_fb_kernel(
    const float* __restrict__ event_out, const int* __restrict__ et,
    const int* __restrict__ labs, float* __restrict__ cumT,
    int* __restrict__ tlA, int S)
{
    const int gid = blockIdx.x * 64 + threadIdx.x;
    const int i = gid / S;
    const int s = gid - i * S;
    const float4* __restrict__ row =
        reinterpret_cast<const float4*>(event_out + (size_t)gid * T_CONST);
    float* __restrict__ base = cumT + (size_t)i * T_CONST * S + s;
    float run = 0.f;
    #pragma unroll
    for (int c = 0; c < T_CONST / 4; ++c) {
        const float4 v = row[c];
        const float c0 = run + v.x;
        const float c1 = c0 + v.y;
        const float c2 = c1 + v.z;
        const float c3 = c2 + v.w;
        base[(size_t)(4 * c + 0) * S] = c0;
        base[(size_t)(4 * c + 1) * S] = c1;
        base[(size_t)(4 * c + 2) * S] = c2;
        base[(size_t)(4 * c + 3) * S] = c3;
        run = c3;
    }
    const int t   = et[s * E_CONST + i];
    const int lab = labs[s * E_CONST + i];
    tlA[i * S + s] = (t & 0xffff) | (lab << 16);
}

__global__ __launch_bounds__(256) void pair_fb_kernel(
    const float* __restrict__ cumT, const int* __restrict__ tlA,
    float* __restrict__ partials, int S)
{
    const int bx = blockIdx.x;
    const int i = bx / S;
    const int k = bx - i * S;
    const int base = i * S;
    const int tlk = tlA[base + k];
    const int t_k = tlk & 0xffff;
    const int lab_k = tlk >> 16;
    const bool doF = (lab_k == 1);
    const bool doB = (t_k > 0);
    float sum = 0.f;
    if (doF || doB) {
        const int cb = lab_k ? (t_k > 0 ? t_k - 1 : 0) : t_k;
        const float* __restrict__ colF = cumT + ((size_t)i * T_CONST + t_k) * S;
        const float* __restrict__ colB = cumT + ((size_t)i * T_CONST + cb)  * S;
        const float vf_k = colF[k];
        const float vb_k = colB[k];
        const int* __restrict__ tlp = tlA + base;
        for (int s = threadIdx.x; s < S; s += 256) {
            const int tls = tlp[s];
            const int t_s = tls & 0xffff;
            const int lab_s = tls >> 16;
            if (doF) {
                const float vs = colF[s];
                const bool c = (t_s > t_k) | ((t_s == t_k) & (lab_s == 0));
                if (c & (vs > vf_k)) sum += __expf((vs - vf_k) * C10);
            }
            if (doB) {
                const float vs = colB[s];
                const bool c = (t_s <= cb) & (lab_s == 1);
                if (c & (vb_k > vs)) sum += __expf((vb_k - vs) * C10);
            }
        }
    }
    for (int off = 32; off > 0; off >>= 1) sum += __shfl_down(sum, off, 64);
    __shared__ float wsum[4];
    const int lane = threadIdx.x & 63, wd = threadIdx.x >> 6;
    if (lane == 0) wsum[wd] = sum;
    __syncthreads();
    if (threadIdx.x == 0) partials[bx] = wsum[0] + wsum[1] + wsum[2] + wsum[3];
}

extern "C" void kernel_launch(void* const* d_in, const int* in_sizes, int n_in,
                              void* d_out, int out_size, void* d_ws, size_t ws_size,
                              hipStream_t stream)
{
    const float* event_out = (const float*)d_in[0];  // (E,S,T) fp32
    const int*   et        = (const int*)d_in[1];    // (S,E) int32
    const int*   labsp     = (const int*)d_in[2];    // (S,E) int32
    const int S = in_sizes[1] / E_CONST;             // 8192

    const size_t colElems = (size_t)E_CONST * T_CONST * S;
    const size_t esElems  = (size_t)E_CONST * S;
    const int    gpBlocks = E_CONST * T_CONST * 2 * SPLIT;   // 2400

    char* p = (char*)d_ws;
    float* cumT     = (float*)p; p += colElems * 4;
    int*   perm     = (int*)p;   p += esElems * 4;
    int*   binStart = (int*)p;   p += (size_t)E_CONST * 2 * T_CONST * 4;
    float* partials = (float*)p; p += (size_t)gpBlocks * 4;
    const size_t needed = (size_t)(p - (char*)d_ws);
    const size_t fallback_needed = colElems * 4 + esElems * 4 * 2;

    const int prepBlocks = (E_CONST * S) / 64;       // 384 (S % 64 == 0)

    // main path requires: rows divisible by 64, and chunk == 2048 (= 8*256)
    if (ws_size >= needed && (E_CONST * S) % 64 == 0 && (S / SPLIT) == 2048) {
        hipLaunchKernelGGL(combo_kernel, dim3(prepBlocks + E_CONST), dim3(512), 0, stream,
                           event_out, et, labsp, cumT, perm, binStart,
                           prepBlocks, S);
        hipLaunchKernelGGL(grouppair_kernel, dim3(gpBlocks), dim3(256), 0, stream,
                           cumT, perm, et, labsp, binStart, partials, S);
        hipLaunchKernelGGL(reduce_kernel, dim3(1), dim3(1024), 0, stream,
                           partials, gpBlocks, (float*)d_out);
    } else if (ws_size >= fallback_needed) {
        const int nB = E_CONST * S;
        float* cumT2     = (float*)d_ws;
        int*   tlA2      = (int*)(cumT2 + colElems);
        float* partials2 = (float*)(tlA2 + esElems);
        hipLaunchKernelGGL(prep_fb_kernel, dim3(E_CONST * S / 64), dim3(64), 0, stream,
                           event_out, et, labsp, cumT2, tlA2, S);
        hipLaunchKernelGGL(pair_fb_kernel, dim3(nB), dim3(256), 0, stream,
                           cumT2, tlA2, partials2, S);
        hipLaunchKernelGGL(reduce_kernel, dim3(1), dim3(1024), 0, stream,
                           partials2, nB, (float*)d_out);
    }
}